// Round 8
// baseline (316.191 us; speedup 1.0000x reference)
//
#include <hip/hip_runtime.h>

// Shapes (fixed): B=2, S=2048, E=1024, H=16, D=64, R=8, M=B*S=4096
typedef __attribute__((ext_vector_type(8))) _Float16 f16x8;
typedef __attribute__((ext_vector_type(4))) _Float16 f16x4;
typedef __attribute__((ext_vector_type(4))) float f32x4;

static __device__ __forceinline__ f16x4 pack4(float a, float b, float c, float d) {
    f16x4 r;
    auto p0 = __builtin_amdgcn_cvt_pkrtz(a, b);
    auto p1 = __builtin_amdgcn_cvt_pkrtz(c, d);
    r[0] = p0[0]; r[1] = p0[1]; r[2] = p1[0]; r[3] = p1[1];
    return r;
}

static __device__ __forceinline__ f16x8 cvt8(float4 u0, float4 u1) {
    f16x8 r;
    auto p = __builtin_amdgcn_cvt_pkrtz(u0.x, u0.y); r[0] = p[0]; r[1] = p[1];
    p = __builtin_amdgcn_cvt_pkrtz(u0.z, u0.w);      r[2] = p[0]; r[3] = p[1];
    p = __builtin_amdgcn_cvt_pkrtz(u1.x, u1.y);      r[4] = p[0]; r[5] = p[1];
    p = __builtin_amdgcn_cvt_pkrtz(u1.z, u1.w);      r[6] = p[0]; r[7] = p[1];
    return r;
}

// ---------------- tsplit_w16: W fp32 [K][N] -> tiled swizzled fp16 [nb][kt][row][chunk] ----------------
// element (row r, physical chunk c, j) = W[kt*64 + (c^(r&7))*8 + j][nb*64 + r]
__global__ __launch_bounds__(256) void tsplit_w16(const float* __restrict__ w0, const float* __restrict__ w1,
                                                  const float* __restrict__ w2, const float* __restrict__ w3,
                                                  _Float16* __restrict__ th) {
    const float* W = blockIdx.z == 0 ? w0 : blockIdx.z == 1 ? w1 : blockIdx.z == 2 ? w2 : w3;
    _Float16* oh = th + (size_t)blockIdx.z * 1048576;
    __shared__ float t[64][65];  // [n_local][k_local]
    const int tid = threadIdx.x;
    const int kt = blockIdx.x, nb = blockIdx.y;
    const int k0 = kt * 64, n0 = nb * 64;
    const int c = tid & 15, r = tid >> 4;
#pragma unroll
    for (int i = 0; i < 4; ++i) {
        const int row = r + i * 16;  // k-local
        const float4 v4 = *(const float4*)&W[(size_t)(k0 + row) * 1024 + n0 + c * 4];
        t[c * 4 + 0][row] = v4.x;
        t[c * 4 + 1][row] = v4.y;
        t[c * 4 + 2][row] = v4.z;
        t[c * 4 + 3][row] = v4.w;
    }
    __syncthreads();
    const size_t tb = (size_t)(nb * 16 + kt) * 4096;
#pragma unroll
    for (int i = 0; i < 2; ++i) {
        const int cid = tid * 2 + i;
        const int rr = cid >> 3, cc = cid & 7;
        const int ksrc = (cc ^ (rr & 7)) * 8;
        f16x8 hv;
#pragma unroll
        for (int j = 0; j < 8; ++j) hv[j] = (_Float16)t[rr][ksrc + j];
        *(f16x8*)&oh[tb + cid * 8] = hv;
    }
}

// ---------------- LoRA first stage: XA[m][r] = sum_k X[m][k] * WA[k][r] ----------------
__global__ __launch_bounds__(256) void lora_xa(const float* __restrict__ X,
                                               const float* __restrict__ WA,
                                               float* __restrict__ XA) {
    const int tid = threadIdx.x;
    const int w = tid >> 6, lane = tid & 63;
    const int m = blockIdx.x * 4 + w;
    const float* xrow = X + (size_t)m * 1024;
    float s[8] = {};
#pragma unroll
    for (int i = 0; i < 4; ++i) {
        const int k = lane * 4 + i * 256;
        const float4 x4 = *(const float4*)&xrow[k];
        const float xs[4] = {x4.x, x4.y, x4.z, x4.w};
#pragma unroll
        for (int j = 0; j < 4; ++j) {
            const float* wr = WA + (size_t)(k + j) * 8;
            const float xv = xs[j];
#pragma unroll
            for (int rr = 0; rr < 8; ++rr) s[rr] = fmaf(xv, wr[rr], s[rr]);
        }
    }
#pragma unroll
    for (int rr = 0; rr < 8; ++rr) {
        float v = s[rr];
        v += __shfl_xor(v, 32);
        v += __shfl_xor(v, 16);
        v += __shfl_xor(v, 8);
        v += __shfl_xor(v, 4);
        v += __shfl_xor(v, 2);
        v += __shfl_xor(v, 1);
        if (lane == 0) XA[(size_t)m * 8 + rr] = v;
    }
}

// ---------------- single-pass fp16 MFMA GEMM (round-5 proven structure) ----------------
// A: fp32 [4096][1024] (converted during staging) or fp16 if AF16.
// Bt: fp16 tiled swizzled. Block 64x64, BK=64, 4 waves 2x2. Grid (64,16).
// OUT: 0 = fp32 [m][1024]; 1 = fp16 [B,H,S,D]; 2 = fp16 vT [B,H,D,S].
template <int OUT, bool LORA, bool AF16>
__global__ __launch_bounds__(256) void gemm_f16(const void* __restrict__ Aptr,
                                                const _Float16* __restrict__ Bt,
                                                const float* __restrict__ bias,
                                                const float* __restrict__ XA,
                                                const float* __restrict__ WB,
                                                float scale,
                                                void* __restrict__ outp) {
    __shared__ _Float16 Ahs[4096], Bhs[4096];
    const int tid = threadIdx.x;
    const int w = tid >> 6, l = tid & 63;
    const int lm = l & 15, g = l >> 4;
    const int wm = w >> 1, wn = w & 1;
    const int m0 = blockIdx.x * 64, nb = blockIdx.y, n0 = nb * 64;

    const int j0 = tid * 2;
    const int sa = j0 >> 3, ca = j0 & 7;
    const int csw0 = ((ca ^ (sa & 7)) * 8);
    const int csw1 = (((ca + 1) ^ (sa & 7)) * 8);
    const float* Af = (const float*)Aptr + (size_t)(m0 + sa) * 1024;
    const _Float16* Af16 = (const _Float16*)Aptr + (size_t)(m0 + sa) * 1024;
    const _Float16* Bp = Bt + (size_t)nb * 65536 + j0 * 8;
    const int ldsO = j0 * 8;

    int afo[2][2], bfo[2][2];
#pragma unroll
    for (int t = 0; t < 2; ++t)
#pragma unroll
        for (int kc = 0; kc < 2; ++kc) {
            const int ar = wm * 32 + t * 16 + lm;
            const int br = wn * 32 + t * 16 + lm;
            afo[t][kc] = ar * 64 + (((kc * 4 + g) ^ (ar & 7)) * 8);
            bfo[t][kc] = br * 64 + (((kc * 4 + g) ^ (br & 7)) * 8);
        }

    f32x4 acc[2][2] = {};
    f16x8 ra0, ra1, rb0, rb1;

#define LOADA(ko, r0, r1)                                                        \
    if (AF16) {                                                                  \
        r0 = *(const f16x8*)&Af16[(ko) + csw0];                                  \
        r1 = *(const f16x8*)&Af16[(ko) + csw1];                                  \
    } else {                                                                     \
        r0 = cvt8(*(const float4*)&Af[(ko) + csw0], *(const float4*)&Af[(ko) + csw0 + 4]); \
        r1 = cvt8(*(const float4*)&Af[(ko) + csw1], *(const float4*)&Af[(ko) + csw1 + 4]); \
    }

    // prologue: k-tile 0
    LOADA(0, ra0, ra1)
    rb0 = *(const f16x8*)&Bp[0];
    rb1 = *(const f16x8*)&Bp[8];
    *(f16x8*)&Ahs[ldsO] = ra0;
    *(f16x8*)&Ahs[ldsO + 8] = ra1;
    *(f16x8*)&Bhs[ldsO] = rb0;
    *(f16x8*)&Bhs[ldsO + 8] = rb1;
    __syncthreads();

    for (int kt = 0; kt < 16; ++kt) {
        const bool more = kt < 15;
        if (more) {
            const int ko = (kt + 1) * 64;
            const int bo = (kt + 1) * 4096;
            LOADA(ko, ra0, ra1)
            rb0 = *(const f16x8*)&Bp[bo];
            rb1 = *(const f16x8*)&Bp[bo + 8];
        }
#pragma unroll
        for (int kc = 0; kc < 2; ++kc) {
            f16x8 ah[2], bh[2];
#pragma unroll
            for (int i = 0; i < 2; ++i) {
                ah[i] = *(const f16x8*)&Ahs[afo[i][kc]];
                bh[i] = *(const f16x8*)&Bhs[bfo[i][kc]];
            }
            __builtin_amdgcn_s_setprio(1);
#pragma unroll
            for (int mt = 0; mt < 2; ++mt)
#pragma unroll
                for (int nt = 0; nt < 2; ++nt)
                    acc[mt][nt] = __builtin_amdgcn_mfma_f32_16x16x32_f16(ah[mt], bh[nt], acc[mt][nt], 0, 0, 0);
            __builtin_amdgcn_s_setprio(0);
        }
        if (more) {
            __syncthreads();
            *(f16x8*)&Ahs[ldsO] = ra0;
            *(f16x8*)&Ahs[ldsO + 8] = ra1;
            *(f16x8*)&Bhs[ldsO] = rb0;
            *(f16x8*)&Bhs[ldsO + 8] = rb1;
            __syncthreads();
        }
    }
#undef LOADA

    // epilogue: bias + optional LoRA + scale
    const int nbase = n0 + wn * 32;
    const int head = nb;  // BN=64 == one head
    float bias2[2];
#pragma unroll
    for (int nt = 0; nt < 2; ++nt) bias2[nt] = bias[nbase + nt * 16 + lm];
    float wbv[8][2];
    if (LORA) {
#pragma unroll
        for (int rr = 0; rr < 8; ++rr)
#pragma unroll
            for (int nt = 0; nt < 2; ++nt) wbv[rr][nt] = WB[rr * 1024 + nbase + nt * 16 + lm];
    }
#pragma unroll
    for (int mt = 0; mt < 2; ++mt) {
        float ov[2][4];
#pragma unroll
        for (int r = 0; r < 4; ++r) {
            const int m = m0 + wm * 32 + mt * 16 + g * 4 + r;
            float xa8[8];
            if (LORA) {
#pragma unroll
                for (int rr = 0; rr < 8; ++rr) xa8[rr] = XA[(size_t)m * 8 + rr];
            }
#pragma unroll
            for (int nt = 0; nt < 2; ++nt) {
                float o = acc[mt][nt][r] + bias2[nt];
                if (LORA) {
#pragma unroll
                    for (int rr = 0; rr < 8; ++rr) o = fmaf(xa8[rr], wbv[rr][nt], o);
                }
                o *= scale;
                ov[nt][r] = o;
                if (OUT == 0) {
                    ((float*)outp)[(size_t)m * 1024 + nbase + nt * 16 + lm] = o;
                } else if (OUT == 1) {
                    const int b = m >> 11, s = m & 2047;
                    ((_Float16*)outp)[((size_t)(b * 16 + head) * 2048 + s) * 64 + wn * 32 + nt * 16 + lm] = (_Float16)o;
                }
            }
        }
        if (OUT == 2) {
            // vT [B,H,D,S] fp16: 4 consecutive s per (mt,nt)
            const int b = m0 >> 11;
            const int sb = (m0 & 2047) + wm * 32 + mt * 16 + g * 4;
#pragma unroll
            for (int nt = 0; nt < 2; ++nt) {
                const int d = wn * 32 + nt * 16 + lm;
                const f16x4 pv = pack4(ov[nt][0], ov[nt][1], ov[nt][2], ov[nt][3]);
                *(f16x4*)&((_Float16*)outp)[((size_t)(b * 16 + head) * 64 + d) * 2048 + sb] = pv;
            }
        }
    }
}

// ---------------- flash attention v5: ZERO shared memory, zero barriers ----------------
// qh/kh: f16 [B,H,S,D] (Q pre-scaled by 0.125*log2e). vT: f16 [B,H,D,S]. ao: f16 [4096][1024].
// 128 thr = 2 waves; wave owns 32 q rows. Grid 1024: bh = blk&31 (XCD-local KV), qt = blk>>5.
// K and V fragments are loaded directly from global (L2-resident: 0.5 MB KV per bh,
// 4 bh per XCD). S^T = mfma(K,Q): lane (g,m) holds P[kv=nt*16+g*4+r][q=m], which is
// exactly the B-fragment of mfma_f32_16x16x16f16 -> PV consumes P from registers.
__global__ __launch_bounds__(128) void flash_attn5(const _Float16* __restrict__ qh,
                                                   const _Float16* __restrict__ kh,
                                                   const _Float16* __restrict__ vT,
                                                   _Float16* __restrict__ ao) {
    const int tid = threadIdx.x;
    const int w = tid >> 6, l = tid & 63;
    const int m = l & 15, g = l >> 4;
    const int bh = blockIdx.x & 31, qt = blockIdx.x >> 5;
    const _Float16* Qb = qh + (size_t)bh * 131072;
    const _Float16* Kl = kh + (size_t)bh * 131072 + m * 64 + g * 8;  // lane K base
    const _Float16* Vb = vT + (size_t)bh * 131072;
    const int q0 = qt * 64 + w * 32;

    // Q fragments (B-operand of QK^T): col q = m, k = kc*32 + g*8 + j
    f16x8 qf[2][2];
#pragma unroll
    for (int qg = 0; qg < 2; ++qg) {
        const _Float16* qrow = Qb + (size_t)(q0 + qg * 16 + m) * 64 + g * 8;
        qf[qg][0] = *(const f16x8*)(qrow);
        qf[qg][1] = *(const f16x8*)(qrow + 32);
    }
    // V row bases: A-frag of PV (16x16x16): lane (g,m): row d = dt*16+m, k = g*4+j
    const _Float16* Vrow[4];
#pragma unroll
    for (int dt = 0; dt < 4; ++dt) Vrow[dt] = Vb + (size_t)(dt * 16 + m) * 2048 + g * 4;

    f32x4 acc_o[2][4] = {};  // acc_o[qg][dt][r] = O[q=m][d=dt*16+g*4+r]
    float lsum[2] = {0.f, 0.f};

    for (int t = 0; t < 32; ++t) {
        // K fragments direct from global: A-frag row kv = nt*16+m, k = kc*32+g*8+j
        const _Float16* Kt = Kl + t * 4096;
        f16x8 kf[4][2];
#pragma unroll
        for (int nt = 0; nt < 4; ++nt)
#pragma unroll
            for (int kc = 0; kc < 2; ++kc)
                kf[nt][kc] = *(const f16x8*)(Kt + nt * 1024 + kc * 32);
        // V fragments direct from global
        f16x4 vf[4][4];
#pragma unroll
        for (int dt = 0; dt < 4; ++dt)
#pragma unroll
            for (int nt = 0; nt < 4; ++nt)
                vf[dt][nt] = *(const f16x4*)(Vrow[dt] + t * 64 + nt * 16);

        // S^T = K · Q^T
        f32x4 s[2][4] = {};
        __builtin_amdgcn_s_setprio(1);
#pragma unroll
        for (int nt = 0; nt < 4; ++nt)
#pragma unroll
            for (int kc = 0; kc < 2; ++kc) {
                s[0][nt] = __builtin_amdgcn_mfma_f32_16x16x32_f16(kf[nt][kc], qf[0][kc], s[0][nt], 0, 0, 0);
                s[1][nt] = __builtin_amdgcn_mfma_f32_16x16x32_f16(kf[nt][kc], qf[1][kc], s[1][nt], 0, 0, 0);
            }
        __builtin_amdgcn_s_setprio(0);

        // softmax numerator (scale pre-folded into Q): bare exp2 + f32 partial sums
        float p[2][4][4];
#pragma unroll
        for (int qg = 0; qg < 2; ++qg) {
#pragma unroll
            for (int nt = 0; nt < 4; ++nt)
#pragma unroll
                for (int r = 0; r < 4; ++r) p[qg][nt][r] = exp2f(s[qg][nt][r]);
            lsum[qg] += (((p[qg][0][0] + p[qg][0][1]) + (p[qg][0][2] + p[qg][0][3])) +
                         ((p[qg][1][0] + p[qg][1][1]) + (p[qg][1][2] + p[qg][1][3]))) +
                        (((p[qg][2][0] + p[qg][2][1]) + (p[qg][2][2] + p[qg][2][3])) +
                         ((p[qg][3][0] + p[qg][3][1]) + (p[qg][3][2] + p[qg][3][3])));
        }
        // P -> fp16 fragments, in-register
        f16x4 pf[2][4];
#pragma unroll
        for (int qg = 0; qg < 2; ++qg)
#pragma unroll
            for (int nt = 0; nt < 4; ++nt)
                pf[qg][nt] = pack4(p[qg][nt][0], p[qg][nt][1], p[qg][nt][2], p[qg][nt][3]);

        // O^T += V^T · P : K=16 MFMAs, both operands from registers
        __builtin_amdgcn_s_setprio(1);
#pragma unroll
        for (int nt = 0; nt < 4; ++nt)
#pragma unroll
            for (int dt = 0; dt < 4; ++dt) {
                acc_o[0][dt] = __builtin_amdgcn_mfma_f32_16x16x16f16(vf[dt][nt], pf[0][nt], acc_o[0][dt], 0, 0, 0);
                acc_o[1][dt] = __builtin_amdgcn_mfma_f32_16x16x16f16(vf[dt][nt], pf[1][nt], acc_o[1][dt], 0, 0, 0);
            }
        __builtin_amdgcn_s_setprio(0);
    }

    // normalize + write ao fp16 [4096][1024] = [b][s][h*64+d]
    const int b = bh >> 4, h = bh & 15;
#pragma unroll
    for (int qg = 0; qg < 2; ++qg) {
        float v = lsum[qg];
        v += __shfl_xor(v, 16);
        v += __shfl_xor(v, 32);
        const float inv = 1.f / v;
        const int srow = q0 + qg * 16 + m;
        _Float16* orow = ao + ((size_t)(b * 2048 + srow)) * 1024 + h * 64;
#pragma unroll
        for (int dt = 0; dt < 4; ++dt) {
            const f16x4 o = pack4(acc_o[qg][dt][0] * inv, acc_o[qg][dt][1] * inv,
                                  acc_o[qg][dt][2] * inv, acc_o[qg][dt][3] * inv);
            *(f16x4*)&orow[dt * 16 + g * 4] = o;
        }
    }
}

extern "C" void kernel_launch(void* const* d_in, const int* in_sizes, int n_in,
                              void* d_out, int out_size, void* d_ws, size_t ws_size,
                              hipStream_t stream) {
    const float* q    = (const float*)d_in[0];
    const float* k    = (const float*)d_in[1];
    const float* v    = (const float*)d_in[2];
    const float* wq   = (const float*)d_in[3];
    const float* bq   = (const float*)d_in[4];
    const float* wq_a = (const float*)d_in[5];
    const float* wq_b = (const float*)d_in[6];
    const float* wk   = (const float*)d_in[7];
    const float* bk   = (const float*)d_in[8];
    const float* wv   = (const float*)d_in[9];
    const float* bv   = (const float*)d_in[10];
    const float* wv_a = (const float*)d_in[11];
    const float* wv_b = (const float*)d_in[12];
    const float* wo   = (const float*)d_in[13];
    const float* bo   = (const float*)d_in[14];
    float* out = (float*)d_out;

    char* wsb = (char*)d_ws;
    _Float16* Wt  = (_Float16*)(wsb);                   // 8 MB: 4x tiled fp16 weights
    _Float16* qhF = (_Float16*)(wsb + (8u << 20));      // 8 MB [B,H,S,D], pre-scaled
    _Float16* khF = (_Float16*)(wsb + (16u << 20));     // 8 MB [B,H,S,D]
    _Float16* vTF = (_Float16*)(wsb + (24u << 20));     // 8 MB [B,H,D,S]
    _Float16* aoF = (_Float16*)(wsb + (32u << 20));     // 8 MB [4096][1024]
    float* xaq    = (float*)(wsb + (40u << 20));        // 128 KB
    float* xav    = (float*)(wsb + (40u << 20) + (128u << 10));

    const dim3 ggrid(64, 16);
    const float qscale = 0.18033688f;  // (1/8) * log2(e)

    tsplit_w16<<<dim3(16, 16, 4), 256, 0, stream>>>(wq, wk, wv, wo, Wt);
    lora_xa<<<1024, 256, 0, stream>>>(q, wq_a, xaq);
    lora_xa<<<1024, 256, 0, stream>>>(v, wv_a, xav);

    gemm_f16<1, true, false><<<ggrid, 256, 0, stream>>>(q, Wt, bq, xaq, wq_b, qscale, qhF);
    gemm_f16<1, false, false><<<ggrid, 256, 0, stream>>>(k, Wt + 1048576, bk, nullptr, nullptr, 1.f, khF);
    gemm_f16<2, true, false><<<ggrid, 256, 0, stream>>>(v, Wt + 2097152, bv, xav, wv_b, 1.f, vTF);

    flash_attn5<<<1024, 128, 0, stream>>>(qhF, khF, vTF, aoF);

    gemm_f16<0, false, true><<<ggrid, 256, 0, stream>>>(aoF, Wt + 3145728, bo, nullptr, nullptr, 1.f, out);
}